// Round 3
// baseline (423.513 us; speedup 1.0000x reference)
//
#include <hip/hip_runtime.h>

#define NN   8192
#define NE   262144
#define IND  128
#define HIDD 256

typedef __bf16 v8bf __attribute__((ext_vector_type(8)));
typedef float  v4f  __attribute__((ext_vector_type(4)));

__device__ __forceinline__ float bf2f(unsigned short u) {
  unsigned int v = ((unsigned int)u) << 16;
  return __builtin_bit_cast(float, v);
}
__device__ __forceinline__ unsigned short f2bf(float f) {
  unsigned int u = __builtin_bit_cast(unsigned int, f);
  u += 0x7FFF + ((u >> 16) & 1);   // RNE
  return (unsigned short)(u >> 16);
}

// ---------------- weight preprocessing (fp32 -> bf16) ----------------
// W1[n][k] = k<128 ? wl1[n][k] : wr1[n][k-128]   (256 x 256)
__global__ void k_buildW1(const float* __restrict__ wl1,
                          const float* __restrict__ wr1,
                          unsigned short* __restrict__ W1) {
  int t = blockIdx.x * 256 + threadIdx.x;   // 65536
  int n = t >> 8, k = t & 255;
  float v = (k < 128) ? wl1[n * 128 + k] : wr1[n * 128 + (k - 128)];
  W1[t] = f2bf(v);
}
// W2[n][k] = k<256 ? wl2[n][k] : wr2[n][k-256]   (256 x 512)
__global__ void k_buildW2(const float* __restrict__ wl2,
                          const float* __restrict__ wr2,
                          unsigned short* __restrict__ W2) {
  int t = blockIdx.x * 256 + threadIdx.x;   // 131072
  int n = t >> 9, k = t & 511;
  float v = (k < 256) ? wl2[n * 256 + k] : wr2[n * 256 + (k - 256)];
  W2[t] = f2bf(v);
}
// v_l[k] = sum_n w_out[n][k]*w_edge[n];  v_r[k] = sum_n w_out[n][k]*w_edge[256+n]
// c[0] = sum_n b_out[n]*w_edge[n]; c[1] = sum_n b_out[n]*w_edge[256+n]  (all fp32)
__global__ void k_vlr(const float* __restrict__ w_out,
                      const float* __restrict__ b_out,
                      const float* __restrict__ w_edge,
                      float* __restrict__ vl, float* __restrict__ vr,
                      float* __restrict__ c2) {
  int k = threadIdx.x;            // one block, 256 threads
  float al = 0.f, ar = 0.f;
  for (int n = 0; n < 256; n++) {
    float w = w_out[n * 256 + k];
    al += w * w_edge[n];
    ar += w * w_edge[256 + n];
  }
  vl[k] = al; vr[k] = ar;
  __shared__ float red[256];
  red[k] = b_out[k] * w_edge[k];
  __syncthreads();
  for (int s = 128; s > 0; s >>= 1) { if (k < s) red[k] += red[k + s]; __syncthreads(); }
  if (k == 0) c2[0] = red[0];
  __syncthreads();
  red[k] = b_out[k] * w_edge[256 + k];
  __syncthreads();
  for (int s = 128; s > 0; s >>= 1) { if (k < s) red[k] += red[k + s]; __syncthreads(); }
  if (k == 0) c2[1] = red[0];
}

// ---------------- CSR build ----------------
__global__ void k_count(const int* __restrict__ dst, int* __restrict__ counts) {
  int e = blockIdx.x * 256 + threadIdx.x;
  if (e < NE) atomicAdd(&counts[dst[e]], 1);
}
// single block, 256 threads, 32 elems each
__global__ void k_scan(const int* __restrict__ counts, int* __restrict__ offs,
                       int* __restrict__ curs, float* __restrict__ ideg) {
  __shared__ int sums[256];
  int t = threadIdx.x;
  int base = t * 32;
  int s = 0;
  for (int i = 0; i < 32; i++) s += counts[base + i];
  sums[t] = s;
  __syncthreads();
  for (int off = 1; off < 256; off <<= 1) {
    int v = (t >= off) ? sums[t - off] : 0;
    __syncthreads();
    sums[t] += v;
    __syncthreads();
  }
  int run = (t == 0) ? 0 : sums[t - 1];
  for (int i = 0; i < 32; i++) {
    int c = counts[base + i];
    offs[base + i] = run;
    curs[base + i] = run;
    ideg[base + i] = 1.0f / (float)(c > 0 ? c : 1);
    run += c;
  }
}
__global__ void k_fill(const int* __restrict__ src, const int* __restrict__ dst,
                       int* __restrict__ curs, int* __restrict__ csr) {
  int e = blockIdx.x * 256 + threadIdx.x;
  if (e < NE) {
    int d = dst[e];
    int p = atomicAdd(&curs[d], 1);
    csr[p] = src[e];
  }
}

// ---------------- copy x (fp32) into right half of A1 as bf16 ----------------
__global__ void k_copyx(const float* __restrict__ x, unsigned short* __restrict__ A1) {
  int t = blockIdx.x * 256 + threadIdx.x;  // 131072 threads, 8 elems each
  int row = t >> 4, c8 = (t & 15) << 3;
  const float* xp = &x[row * 128 + c8];
  float4 a = *(const float4*)xp;
  float4 b = *(const float4*)(xp + 4);
  unsigned short o[8];
  o[0] = f2bf(a.x); o[1] = f2bf(a.y); o[2] = f2bf(a.z); o[3] = f2bf(a.w);
  o[4] = f2bf(b.x); o[5] = f2bf(b.y); o[6] = f2bf(b.z); o[7] = f2bf(b.w);
  *(uint4*)&A1[row * 256 + 128 + c8] = *(uint4*)o;
}

// ---------------- gather-mean from fp32 feat (layer 1) ----------------
__global__ void k_gather_f32(const float* __restrict__ feat,
                             unsigned short* __restrict__ outp,
                             const int* __restrict__ offs, const int* __restrict__ counts,
                             const float* __restrict__ ideg, const int* __restrict__ csr) {
  int node = blockIdx.x;
  int t = threadIdx.x;                  // 128 threads
  int start = offs[node], cnt = counts[node];
  const float* fp = feat + t;
  float acc = 0.f;
  int i = 0;
  for (; i + 4 <= cnt; i += 4) {
    int s0 = csr[start + i], s1 = csr[start + i + 1];
    int s2 = csr[start + i + 2], s3 = csr[start + i + 3];
    acc += fp[(size_t)s0 * IND];
    acc += fp[(size_t)s1 * IND];
    acc += fp[(size_t)s2 * IND];
    acc += fp[(size_t)s3 * IND];
  }
  for (; i < cnt; i++) acc += fp[(size_t)csr[start + i] * IND];
  outp[(size_t)node * 256 + t] = f2bf(acc * ideg[node]);
}

// ---------------- gather-mean from bf16 feat (layer 2) ----------------
__global__ void k_gather_bf16(const unsigned short* __restrict__ feat, int fstride, int foff,
                              unsigned short* __restrict__ outp, int ostride, int ooff,
                              const int* __restrict__ offs, const int* __restrict__ counts,
                              const float* __restrict__ ideg, const int* __restrict__ csr) {
  int node = blockIdx.x;
  int t = threadIdx.x;
  int start = offs[node], cnt = counts[node];
  const unsigned short* fp = feat + foff + t;
  float acc = 0.f;
  int i = 0;
  for (; i + 4 <= cnt; i += 4) {
    int s0 = csr[start + i], s1 = csr[start + i + 1];
    int s2 = csr[start + i + 2], s3 = csr[start + i + 3];
    acc += bf2f(fp[(size_t)s0 * fstride]);
    acc += bf2f(fp[(size_t)s1 * fstride]);
    acc += bf2f(fp[(size_t)s2 * fstride]);
    acc += bf2f(fp[(size_t)s3 * fstride]);
  }
  for (; i < cnt; i++) acc += bf2f(fp[(size_t)csr[start + i] * fstride]);
  outp[(size_t)node * ostride + ooff + t] = f2bf(acc * ideg[node]);
}

// ---------------- MFMA GEMM: C = relu(A @ B^T + bias) ----------------
// A: M x K bf16 row-major (stride lda). B: N x K bf16 row-major. bias fp32.
// C: bf16, row stride ldc, column offset coff. Tile 64x64, 4 waves of 2x2 16x16x32 MFMAs.
__global__ __launch_bounds__(256) void k_gemm(
    const unsigned short* __restrict__ A, int lda,
    const unsigned short* __restrict__ B,
    const float* __restrict__ bias,
    unsigned short* __restrict__ C, int ldc, int coff, int K) {
  __shared__ __align__(16) unsigned short As[64][40];
  __shared__ __align__(16) unsigned short Bs[64][40];
  int tid = threadIdx.x;
  int bm = blockIdx.x, bn = blockIdx.y;
  int lane = tid & 63, wave = tid >> 6;
  int wm = (wave & 1) * 32, wn = (wave >> 1) * 32;
  int quad = lane >> 4, l16 = lane & 15;
  int srow = tid >> 2, schunk = (tid & 3) * 8;
  const unsigned short* gA = A + (size_t)(bm * 64 + srow) * lda + schunk;
  const unsigned short* gB = B + (size_t)(bn * 64 + srow) * K + schunk;
  v4f acc[2][2];
  for (int mi = 0; mi < 2; mi++)
    for (int ni = 0; ni < 2; ni++)
      acc[mi][ni] = v4f{0.f, 0.f, 0.f, 0.f};
  for (int k0 = 0; k0 < K; k0 += 32) {
    uint4 va = *(const uint4*)(gA + k0);
    uint4 vb = *(const uint4*)(gB + k0);
    __syncthreads();
    *(uint4*)&As[srow][schunk] = va;
    *(uint4*)&Bs[srow][schunk] = vb;
    __syncthreads();
    v8bf a0 = *(v8bf*)&As[wm + l16][quad * 8];
    v8bf a1 = *(v8bf*)&As[wm + 16 + l16][quad * 8];
    v8bf b0 = *(v8bf*)&Bs[wn + l16][quad * 8];
    v8bf b1 = *(v8bf*)&Bs[wn + 16 + l16][quad * 8];
    acc[0][0] = __builtin_amdgcn_mfma_f32_16x16x32_bf16(a0, b0, acc[0][0], 0, 0, 0);
    acc[0][1] = __builtin_amdgcn_mfma_f32_16x16x32_bf16(a0, b1, acc[0][1], 0, 0, 0);
    acc[1][0] = __builtin_amdgcn_mfma_f32_16x16x32_bf16(a1, b0, acc[1][0], 0, 0, 0);
    acc[1][1] = __builtin_amdgcn_mfma_f32_16x16x32_bf16(a1, b1, acc[1][1], 0, 0, 0);
  }
  for (int mi = 0; mi < 2; mi++) {
    for (int ni = 0; ni < 2; ni++) {
      int col = bn * 64 + wn + ni * 16 + l16;
      float bv = bias[col];
      for (int r = 0; r < 4; r++) {
        int row = bm * 64 + wm + mi * 16 + quad * 4 + r;
        float v = acc[mi][ni][r] + bv;
        v = fmaxf(v, 0.f);
        C[(size_t)row * ldc + coff + col] = f2bf(v);
      }
    }
  }
}

// ---------------- Li/Lj: per-node dots with v_l / v_r ----------------
__global__ void k_lilj(const unsigned short* __restrict__ H2,
                       const float* __restrict__ vl, const float* __restrict__ vr,
                       const float* __restrict__ c2, const float* __restrict__ b_edge,
                       float* __restrict__ Li, float* __restrict__ Lj) {
  int wave = threadIdx.x >> 6, lane = threadIdx.x & 63;
  int node = blockIdx.x * 4 + wave;
  const unsigned short* h = H2 + (size_t)node * 256;
  float al = 0.f, ar = 0.f;
  for (int k = lane; k < 256; k += 64) {
    float hv = bf2f(h[k]);
    al += hv * vl[k];
    ar += hv * vr[k];
  }
  for (int off = 32; off > 0; off >>= 1) {
    al += __shfl_down(al, off);
    ar += __shfl_down(ar, off);
  }
  if (lane == 0) {
    Li[node] = al + c2[0] + b_edge[0];
    Lj[node] = ar + c2[1];
  }
}

// ---------------- outer sum: out[i][j] = fp32(Li[i] + Lj[j]) ----------------
__global__ void k_outer(const float* __restrict__ Li, const float* __restrict__ Lj,
                        float* __restrict__ outp) {
  int t = blockIdx.x * 256 + threadIdx.x;   // 8192*1024 threads, 8 floats each
  int row = t >> 10;
  int jc = (t & 1023) << 3;
  float li = Li[row];
  float4 x0 = *(const float4*)&Lj[jc];
  float4 x1 = *(const float4*)&Lj[jc + 4];
  float4 o0, o1;
  o0.x = li + x0.x; o0.y = li + x0.y; o0.z = li + x0.z; o0.w = li + x0.w;
  o1.x = li + x1.x; o1.y = li + x1.y; o1.z = li + x1.z; o1.w = li + x1.w;
  float* op = &outp[(size_t)row * 8192 + jc];
  *(float4*)op = o0;
  *(float4*)(op + 4) = o1;
}

extern "C" void kernel_launch(void* const* d_in, const int* in_sizes, int n_in,
                              void* d_out, int out_size, void* d_ws, size_t ws_size,
                              hipStream_t stream) {
  const float* x      = (const float*)d_in[0];
  const int*   ei     = (const int*)d_in[1];
  const float* wl1    = (const float*)d_in[2];
  const float* bl1    = (const float*)d_in[3];
  const float* wr1    = (const float*)d_in[4];
  const float* wl2    = (const float*)d_in[5];
  const float* bl2    = (const float*)d_in[6];
  const float* wr2    = (const float*)d_in[7];
  const float* w_out  = (const float*)d_in[8];
  const float* b_out  = (const float*)d_in[9];
  const float* w_edge = (const float*)d_in[10];
  const float* b_edge = (const float*)d_in[11];
  float* outp = (float*)d_out;

  const int* srcp = ei;
  const int* dstp = ei + NE;

  // workspace layout (bytes, 256-aligned)
  const size_t OFF_A1   = 0;                       // 8192*256*2  = 4 MB   [mean1 | x]
  const size_t OFF_A2   = OFF_A1 + 4194304;        // 8192*512*2  = 8 MB   [mean2 | h1]
  const size_t OFF_H2   = OFF_A2 + 8388608;        // 8192*256*2  = 4 MB
  const size_t OFF_W1   = OFF_H2 + 4194304;        // 131072
  const size_t OFF_W2   = OFF_W1 + 131072;         // 262144
  const size_t OFF_VL   = OFF_W2 + 262144;         // 1024
  const size_t OFF_VR   = OFF_VL + 1024;           // 1024
  const size_t OFF_C2   = OFF_VR + 1024;           // 256
  const size_t OFF_CNT  = OFF_C2 + 256;            // 32768
  const size_t OFF_OFFS = OFF_CNT + 32768;         // 32768
  const size_t OFF_CURS = OFF_OFFS + 32768;        // 32768
  const size_t OFF_IDEG = OFF_CURS + 32768;        // 32768
  const size_t OFF_CSR  = OFF_IDEG + 32768;        // 1048576
  const size_t OFF_LI   = OFF_CSR + 1048576;       // 32768
  const size_t OFF_LJ   = OFF_LI + 32768;          // 32768
  const size_t TOTAL    = OFF_LJ + 32768;          // ~18.4 MB
  if (ws_size < TOTAL) return;

  char* ws = (char*)d_ws;
  unsigned short* A1 = (unsigned short*)(ws + OFF_A1);
  unsigned short* A2 = (unsigned short*)(ws + OFF_A2);
  unsigned short* H2 = (unsigned short*)(ws + OFF_H2);
  unsigned short* W1 = (unsigned short*)(ws + OFF_W1);
  unsigned short* W2 = (unsigned short*)(ws + OFF_W2);
  float* VL   = (float*)(ws + OFF_VL);
  float* VR   = (float*)(ws + OFF_VR);
  float* C2   = (float*)(ws + OFF_C2);
  int*   CNT  = (int*)(ws + OFF_CNT);
  int*   OFFS = (int*)(ws + OFF_OFFS);
  int*   CURS = (int*)(ws + OFF_CURS);
  float* IDEG = (float*)(ws + OFF_IDEG);
  int*   CSR  = (int*)(ws + OFF_CSR);
  float* LI   = (float*)(ws + OFF_LI);
  float* LJ   = (float*)(ws + OFF_LJ);

  hipMemsetAsync(CNT, 0, NN * sizeof(int), stream);

  k_buildW1<<<256, 256, 0, stream>>>(wl1, wr1, W1);
  k_buildW2<<<512, 256, 0, stream>>>(wl2, wr2, W2);
  k_vlr<<<1, 256, 0, stream>>>(w_out, b_out, w_edge, VL, VR, C2);
  k_copyx<<<512, 256, 0, stream>>>(x, A1);

  k_count<<<NE / 256, 256, 0, stream>>>(dstp, CNT);
  k_scan<<<1, 256, 0, stream>>>(CNT, OFFS, CURS, IDEG);
  k_fill<<<NE / 256, 256, 0, stream>>>(srcp, dstp, CURS, CSR);

  // layer 1: mean(x) -> A1[:, :128];  h1 = relu(A1 @ W1^T + bl1) -> A2[:, 256:512]
  k_gather_f32<<<NN, 128, 0, stream>>>(x, A1, OFFS, CNT, IDEG, CSR);
  k_gemm<<<dim3(NN / 64, 4), 256, 0, stream>>>(A1, 256, W1, bl1, A2, 512, 256, 256);

  // layer 2: mean(h1) -> A2[:, :256]; h2 = relu(A2 @ W2^T + bl2) -> H2
  k_gather_bf16<<<NN, 256, 0, stream>>>(A2, 512, 256, A2, 512, 0, OFFS, CNT, IDEG, CSR);
  k_gemm<<<dim3(NN / 64, 4), 256, 0, stream>>>(A2, 512, W2, bl2, H2, 256, 0, 512);

  // folded output layer + edge scores
  k_lilj<<<NN / 4, 256, 0, stream>>>(H2, VL, VR, C2, b_edge, LI, LJ);
  k_outer<<<(NN * 1024) / 256, 256, 0, stream>>>(LI, LJ, outp);
}